// Round 9
// baseline (20418.602 us; speedup 1.0000x reference)
//
#include <hip/hip_runtime.h>
#include <hip/hip_fp16.h>

typedef _Float16 half8 __attribute__((ext_vector_type(8)));
typedef float f32x4 __attribute__((ext_vector_type(4)));

#define T_STEPS 512

static __device__ __forceinline__ float sigf(float x) {
    return __builtin_amdgcn_rcpf(1.0f + __builtin_amdgcn_exp2f(-1.44269504088896f * x));
}
static __device__ __forceinline__ float tanhf_fast(float x) {
    return 2.0f * __builtin_amdgcn_rcpf(1.0f + __builtin_amdgcn_exp2f(-2.88539008177793f * x)) - 1.0f;
}

// Persistent LSTM v9: stagingless dataflow.
// s = XCC_ID, jj = rank in XCD. 1 WG/CU (LDS pad + VGPR). Slice p of h lives in
// hbuf[.][s][p] as [16 batches][32 units] fp16 (1KB). Per step, per wave:
//   poll 32 flags (lanes 0-31, s_sleep backoff, acquire-fence per iter)
//   -> one acquire fence -> B-frags loaded DIRECTLY from slices in local L2
//      (16B/lane per slice; L1 shares across the 8 waves; NO h_lds, NO barriers)
//   -> 32 MFMAs (4 chains) -> epilogue -> per-lane 2B scatter publish
//   -> vmcnt(0) -> lane0: LDS pub-counter; 8th wave stores WG flag.
// flag = r  <=>  h(r-1) published in hbuf[(r-1)&1]. Step t needs flag >= t+1.
// Own flag doubles as intra-WG sync (set only when all 8 own waves published).
__global__ __launch_bounds__(512, 2) void lstm_persist(
    const float* __restrict__ y_hist,  // [128][512]
    const float* __restrict__ W_ih,    // [4096]
    const float* __restrict__ W_hh,    // [4096][1024]
    const float* __restrict__ b_ih,    // [4096]
    const float* __restrict__ b_hh,    // [4096]
    const float* __restrict__ fc_W,    // [128][1024]
    const float* __restrict__ fc_b,    // [128]
    const float* __restrict__ h0,      // [128][1024]
    const float* __restrict__ c0,      // [128][1024]
    float* __restrict__ out,           // [128][128]
    _Float16* __restrict__ hbuf0,      // [8][32][16][32] fp16 slices
    _Float16* __restrict__ hbuf1,
    float* __restrict__ hfin,          // fp32 h_T [128][1024]
    unsigned int* __restrict__ flags,  // [8][32] strided 128B: dword ((s*32+j)*32)
    unsigned int* __restrict__ xcnt,   // [8] rank counters (MALL atomics)
    unsigned int* __restrict__ gbar)   // [8] startup barrier (MALL atomics)
{
    __shared__ float y_lds[512][16];   // 32KB, whole y tile
    __shared__ unsigned sjj[2];
    __shared__ unsigned pub_ctr;       // +1 per wave per publish round

    const int tid = threadIdx.x;
    const int l   = tid & 63;
    const int wid = tid >> 6;
    const int q4  = l >> 4;
    const int n   = l & 15;

    if (tid == 0) {
        pub_ctr = 0;
        unsigned x;
        asm volatile("s_getreg_b32 %0, hwreg(HW_REG_XCC_ID)" : "=s"(x));
        x &= 7u;
        sjj[0] = x;
        sjj[1] = atomicAdd(&xcnt[x], 1u) & 31u;   // MALL, memset-safe
    }
    __syncthreads();
    const int s  = (int)sjj[0];
    const int jj = (int)sjj[1];

    // ---- in-kernel flag reset (this XCD's L2), then MALL startup barrier ----
    if (jj == 0 && tid < 32)
        *(volatile unsigned*)&flags[((s << 5) + tid) << 5] = 0u;
    asm volatile("s_waitcnt vmcnt(0)" ::: "memory");
    __syncthreads();
    if (tid == 0) {
        __hip_atomic_fetch_add(&gbar[s], 1u, __ATOMIC_RELAXED, __HIP_MEMORY_SCOPE_AGENT);
        int guard = 0;
        while (__hip_atomic_load(&gbar[s], __ATOMIC_RELAXED, __HIP_MEMORY_SCOPE_AGENT) < 32u) {
            if (++guard > (1 << 20)) break;
        }
    }
    __syncthreads();

    // ---- W_hh -> fp16 A-fragments: wfrag[p] covers k = 32p + 8*q4 + j ----
    half8 wfrag[32];
    {
        const int r16  = l & 15;
        const int u_a  = 4 * wid + (r16 >> 2);
        const int g_a  = r16 & 3;
        const int grow = g_a * 1024 + 32 * jj + u_a;
        const float* wrow = W_hh + (size_t)grow * 1024 + 8 * q4;
        #pragma unroll
        for (int c = 0; c < 32; ++c) {
            f32x4 a0 = *(const f32x4*)(wrow + 32 * c);
            f32x4 a1 = *(const f32x4*)(wrow + 32 * c + 4);
            half8 w;
            w[0]=(_Float16)a0[0]; w[1]=(_Float16)a0[1];
            w[2]=(_Float16)a0[2]; w[3]=(_Float16)a0[3];
            w[4]=(_Float16)a1[0]; w[5]=(_Float16)a1[1];
            w[6]=(_Float16)a1[2]; w[7]=(_Float16)a1[3];
            wfrag[c] = w;
        }
    }

    // ---- per-lane epilogue constants: lane owns (batch n, unit u_e = 4*wid+q4) ----
    const int u_e = 4 * wid + q4;
    float wih_r[4], bias_r[4], creg;
    #pragma unroll
    for (int g = 0; g < 4; ++g) {
        const int gr = g * 1024 + 32 * jj + u_e;
        wih_r[g]  = W_ih[gr];
        bias_r[g] = b_ih[gr] + b_hh[gr];
    }
    creg = c0[(size_t)(16 * s + n) * 1024 + 32 * jj + u_e];

    // ---- preload whole y tile (once) ----
    {
        const int r = tid >> 5, sg = tid & 31;
        const float* yr = y_hist + (size_t)(16 * s + r) * 512;
        #pragma unroll
        for (int e = 0; e < 4; ++e) {
            f32x4 v = *(const f32x4*)(yr + sg * 4 + 128 * e);
            #pragma unroll
            for (int j = 0; j < 4; ++j) y_lds[sg * 4 + 128 * e + j][r] = v[j];
        }
    }
    __syncthreads();   // y_lds ready (the only barrier before the FC)

    _Float16* const g0 = hbuf0 + (s << 14);   // group slice bases (16384 halves)
    _Float16* const g1 = hbuf1 + (s << 14);
    const int loff  = n * 64 + 16 * q4;       // B-frag byte offset within a slice
    const int poff  = (jj << 9) + (n << 5) + u_e;  // publish half-offset in group
    volatile unsigned* const fown = &flags[((s << 5) + jj) << 5];
    const volatile unsigned* const fpoll = flags + (((s << 5) + (l & 31)) << 5);

    // ---- publish round 1: h(0) from h0 -> hbuf0 slices ----
    {
        const float hv0 = h0[(size_t)(16 * s + n) * 1024 + 32 * jj + u_e];
        g0[poff] = (_Float16)hv0;
        asm volatile("s_waitcnt vmcnt(0)" ::: "memory");
        if (l == 0) {
            unsigned old = __hip_atomic_fetch_add(&pub_ctr, 1u, __ATOMIC_RELAXED,
                                                  __HIP_MEMORY_SCOPE_WORKGROUP);
            if (old == 7u) *fown = 1u;
        }
    }

    for (int t = 0; t < T_STEPS; ++t) {
        // ---- wait for h(t): every wave polls all 32 flags, s_sleep backoff ----
        {
            const unsigned tgt = (unsigned)(t + 1);
            int guard = 0;
            for (;;) {
                unsigned fv = *fpoll;
                if (__all((int)(fv >= tgt))) break;
                if (++guard > (1 << 14)) break;
                __builtin_amdgcn_s_sleep(1);
                __builtin_amdgcn_fence(__ATOMIC_ACQUIRE, "agent");
            }
            __builtin_amdgcn_fence(__ATOMIC_ACQUIRE, "agent");  // L1 clean for B loads
        }
        // ---- consume: B-frags straight from slices (local L2 / L1), 4 chains ----
        f32x4 ac0 = {0.f,0.f,0.f,0.f}, ac1 = {0.f,0.f,0.f,0.f};
        f32x4 ac2 = {0.f,0.f,0.f,0.f}, ac3 = {0.f,0.f,0.f,0.f};
        {
            const char* cb = (const char*)((t & 1) ? g1 : g0);
            #pragma unroll
            for (int g = 0; g < 8; ++g) {
                half8 b0 = *(const half8*)(cb + ((g     ) << 10) + loff);
                half8 b1 = *(const half8*)(cb + ((g +  8) << 10) + loff);
                half8 b2 = *(const half8*)(cb + ((g + 16) << 10) + loff);
                half8 b3 = *(const half8*)(cb + ((g + 24) << 10) + loff);
                ac0 = __builtin_amdgcn_mfma_f32_16x16x32_f16(wfrag[g],      b0, ac0, 0, 0, 0);
                ac1 = __builtin_amdgcn_mfma_f32_16x16x32_f16(wfrag[g +  8], b1, ac1, 0, 0, 0);
                ac2 = __builtin_amdgcn_mfma_f32_16x16x32_f16(wfrag[g + 16], b2, ac2, 0, 0, 0);
                ac3 = __builtin_amdgcn_mfma_f32_16x16x32_f16(wfrag[g + 24], b3, ac3, 0, 0, 0);
            }
        }
        // ---- epilogue + per-lane publish of h(t+1) ----
        {
            const float yt = y_lds[t][n];
            float gi = (ac0[0] + ac1[0]) + (ac2[0] + ac3[0]) + yt * wih_r[0] + bias_r[0];
            float gf = (ac0[1] + ac1[1]) + (ac2[1] + ac3[1]) + yt * wih_r[1] + bias_r[1];
            float gg = (ac0[2] + ac1[2]) + (ac2[2] + ac3[2]) + yt * wih_r[2] + bias_r[2];
            float go = (ac0[3] + ac1[3]) + (ac2[3] + ac3[3]) + yt * wih_r[3] + bias_r[3];
            float cn = sigf(gf) * creg + sigf(gi) * tanhf_fast(gg);
            creg = cn;
            float hv = sigf(go) * tanhf_fast(cn);
            _Float16* ob = ((t & 1) ? g0 : g1) + poff;   // h(t+1) -> buf[(t+1)&1]
            *ob = (_Float16)hv;
            if (t == T_STEPS - 1)
                hfin[(size_t)(16 * s + n) * 1024 + 32 * jj + u_e] = hv;
        }
        asm volatile("s_waitcnt vmcnt(0)" ::: "memory");   // publish acked by local L2
        if (l == 0) {
            unsigned old = __hip_atomic_fetch_add(&pub_ctr, 1u, __ATOMIC_RELAXED,
                                                  __HIP_MEMORY_SCOPE_WORKGROUP);
            if (old == 8u * (unsigned)(t + 2) - 1u)   // last of 8 waves this round
                *fown = (unsigned)(t + 2);
        }
    }

    // ---- final FC: WG (s, jj<16) -> batch b = 16s+jj (hfin fp32, same XCD) ----
    if (jj < 16) {
        if (wid == 0) {
            const unsigned tgt = (unsigned)(T_STEPS + 1);
            int guard = 0;
            for (;;) {
                unsigned fv = *fpoll;
                if (__all((int)(fv >= tgt))) break;
                if (++guard > (1 << 15)) break;
                __builtin_amdgcn_s_sleep(1);
                __builtin_amdgcn_fence(__ATOMIC_ACQUIRE, "agent");
            }
        }
        __syncthreads();
        __builtin_amdgcn_fence(__ATOMIC_ACQUIRE, "agent");  // every wave: L1 clean
        float* hT  = (float*)y_lds;       // reuse LDS: 4KB
        float* red = hT + 1024;           // 2KB
        const int b = 16 * s + jj;
        if (tid < 256) {
            f32x4 v = *(const f32x4*)(hfin + (size_t)b * 1024 + tid * 4);
            *(f32x4*)(hT + tid * 4) = v;
        }
        __syncthreads();
        {
            const int o = tid & 127, kq = tid >> 7;
            const float* wr = fc_W + (size_t)o * 1024 + kq * 256;
            const float* hp = hT + kq * 256;
            float p = 0.0f;
            #pragma unroll 8
            for (int i = 0; i < 256; i += 4) {
                f32x4 a = *(const f32x4*)(hp + i);
                f32x4 w = *(const f32x4*)(wr + i);
                p += a[0]*w[0] + a[1]*w[1] + a[2]*w[2] + a[3]*w[3];
            }
            red[kq * 128 + o] = p;
        }
        __syncthreads();
        if (tid < 128) {
            out[(size_t)b * 128 + tid] =
                red[tid] + red[128 + tid] + red[256 + tid] + red[384 + tid] + fc_b[tid];
        }
    }
}

extern "C" void kernel_launch(void* const* d_in, const int* in_sizes, int n_in,
                              void* d_out, int out_size, void* d_ws, size_t ws_size,
                              hipStream_t stream) {
    (void)in_sizes; (void)n_in; (void)out_size; (void)ws_size;
    const float* y_hist = (const float*)d_in[0];
    const float* W_ih   = (const float*)d_in[1];
    const float* W_hh   = (const float*)d_in[2];
    const float* b_ih   = (const float*)d_in[3];
    const float* b_hh   = (const float*)d_in[4];
    const float* fc_W   = (const float*)d_in[5];
    const float* fc_b   = (const float*)d_in[6];
    const float* h0     = (const float*)d_in[7];
    const float* c0     = (const float*)d_in[8];

    // d_ws: hbuf0 (256KB) | hbuf1 (256KB) | hfin (512KB) | flags (32KB strided)
    //       | xcnt (128B) | gbar (128B)
    char* ws = (char*)d_ws;
    _Float16* hbuf0 = (_Float16*)ws;
    _Float16* hbuf1 = (_Float16*)(ws + (256 << 10));
    float*    hfin  = (float*)(ws + (512 << 10));
    unsigned int* flags = (unsigned int*)(ws + (1024 << 10));
    unsigned int* xcnt  = (unsigned int*)(ws + (1024 << 10) + (32 << 10));
    unsigned int* gbar  = (unsigned int*)(ws + (1024 << 10) + (32 << 10) + 128);

    // xcnt/gbar touched only via MALL-scope atomics -> SDMA memset safe.
    // flags reset in-kernel (stale XCD-L2 lines can't be fixed by SDMA).
    hipMemsetAsync(ws + (1024 << 10) + (32 << 10), 0, 1024, stream);
    // 49KB dynamic LDS pad + ~33KB static -> ~82KB/WG -> 1 WG/CU -> 32 WGs/XCD.
    hipLaunchKernelGGL(lstm_persist, dim3(256), dim3(512), 50176, stream,
                       y_hist, W_ih, W_hh, b_ih, b_hh, fc_W, fc_b, h0, c0,
                       (float*)d_out, hbuf0, hbuf1, hfin, flags, xcnt, gbar);
}

// Round 10
// 2307.092 us; speedup vs baseline: 8.8504x; 8.8504x over previous
//
#include <hip/hip_runtime.h>
#include <hip/hip_fp16.h>

typedef _Float16 half8 __attribute__((ext_vector_type(8)));
typedef float f32x4 __attribute__((ext_vector_type(4)));

#define T_STEPS 512
#define BUSY_N  96   // ~1500 cy of independent FMAs (8 chains x 2cy/inst)

static __device__ __forceinline__ float sigf(float x) {
    return __builtin_amdgcn_rcpf(1.0f + __builtin_amdgcn_exp2f(-1.44269504088896f * x));
}
static __device__ __forceinline__ float tanhf_fast(float x) {
    return 2.0f * __builtin_amdgcn_rcpf(1.0f + __builtin_amdgcn_exp2f(-2.88539008177793f * x)) - 1.0f;
}

// Persistent LSTM v10 = round-8 kernel (passing, 2306us) + DPM-clock probe:
// waves 1-7, which in r8 idle at the barrier while wave0 polls, now run a
// fixed ~1500-cycle register-only independent-FMA block (no memory traffic,
// no effect on wave0's poll loop). If low DPM clocks were inflating the
// serial sync chain, every leg shortens; worst case the block is hidden
// in the poll shadow. Everything else identical to round 8.
__global__ __launch_bounds__(512, 2) void lstm_persist(
    const float* __restrict__ y_hist,  // [128][512]
    const float* __restrict__ W_ih,    // [4096]
    const float* __restrict__ W_hh,    // [4096][1024]
    const float* __restrict__ b_ih,    // [4096]
    const float* __restrict__ b_hh,    // [4096]
    const float* __restrict__ fc_W,    // [128][1024]
    const float* __restrict__ fc_b,    // [128]
    const float* __restrict__ h0,      // [128][1024]
    const float* __restrict__ c0,      // [128][1024]
    float* __restrict__ out,           // [128][128]
    unsigned long long* __restrict__ hbuf0,  // [8][4096] u64 = [grp][jjp][n][u] fp16
    unsigned long long* __restrict__ hbuf1,
    float* __restrict__ hfin,                // fp32 h_T [128][1024]
    unsigned int* __restrict__ flags,        // [8][32] strided: flag(s,j) at dword ((s*32+j)*32)
    unsigned int* __restrict__ xcnt,         // [8] rank counters (MALL atomics)
    unsigned int* __restrict__ gbar)         // [8] startup barrier (MALL atomics)
{
    __shared__ _Float16 h_lds[16 * 1024];          // 32KB [n][k], byte^((n&7)<<4)
    __shared__ float    y_lds[512][16];            // 32KB
    __shared__ unsigned long long hout_lds[128];   // 1KB
    __shared__ unsigned sjj[2];

    const int tid = threadIdx.x;
    const int l   = tid & 63;
    const int wid = tid >> 6;
    const int q4  = l >> 4;
    const int n   = l & 15;

    if (tid == 0) {
        unsigned x;
        asm volatile("s_getreg_b32 %0, hwreg(HW_REG_XCC_ID)" : "=s"(x));
        x &= 7u;
        sjj[0] = x;
        sjj[1] = atomicAdd(&xcnt[x], 1u) & 31u;   // MALL, memset-safe
    }
    __syncthreads();
    const int s  = (int)sjj[0];
    const int jj = (int)sjj[1];

    // ---- in-kernel flag reset (this XCD's L2), then MALL startup barrier ----
    if (jj == 0 && tid < 32)
        *(volatile unsigned*)&flags[((s << 5) + tid) << 5] = 0u;
    asm volatile("s_waitcnt vmcnt(0)" ::: "memory");
    __syncthreads();
    if (tid == 0) {
        __hip_atomic_fetch_add(&gbar[s], 1u, __ATOMIC_RELAXED, __HIP_MEMORY_SCOPE_AGENT);
        int guard = 0;
        while (__hip_atomic_load(&gbar[s], __ATOMIC_RELAXED, __HIP_MEMORY_SCOPE_AGENT) < 32u) {
            if (++guard > (1 << 20)) break;
        }
    }
    __syncthreads();

    // ---- W_hh -> fp16 A-fragments (full K): k = 32c + 8*q4 + j ----
    half8 wfrag[32];
    {
        const int r16  = l & 15;
        const int u_a  = 4 * wid + (r16 >> 2);
        const int g_a  = r16 & 3;
        const int grow = g_a * 1024 + 32 * jj + u_a;
        const float* wrow = W_hh + (size_t)grow * 1024 + 8 * q4;
        #pragma unroll
        for (int c = 0; c < 32; ++c) {
            f32x4 a0 = *(const f32x4*)(wrow + 32 * c);
            f32x4 a1 = *(const f32x4*)(wrow + 32 * c + 4);
            half8 w;
            w[0]=(_Float16)a0[0]; w[1]=(_Float16)a0[1];
            w[2]=(_Float16)a0[2]; w[3]=(_Float16)a0[3];
            w[4]=(_Float16)a1[0]; w[5]=(_Float16)a1[1];
            w[6]=(_Float16)a1[2]; w[7]=(_Float16)a1[3];
            wfrag[c] = w;
        }
    }

    // ---- per-lane epilogue constants: lane owns (batch n, unit u_e = 4*wid+q4) ----
    const int u_e = 4 * wid + q4;
    float wih_r[4], bias_r[4], creg;
    #pragma unroll
    for (int g = 0; g < 4; ++g) {
        const int gr = g * 1024 + 32 * jj + u_e;
        wih_r[g]  = W_ih[gr];
        bias_r[g] = b_ih[gr] + b_hh[gr];
    }
    creg = c0[(size_t)(16 * s + n) * 1024 + 32 * jj + u_e];

    // ---- preload whole y tile (once) ----
    {
        const int r = tid >> 5, sg = tid & 31;
        const float* yr = y_hist + (size_t)(16 * s + r) * 512;
        #pragma unroll
        for (int e = 0; e < 4; ++e) {
            f32x4 v = *(const f32x4*)(yr + sg * 4 + 128 * e);
            #pragma unroll
            for (int j = 0; j < 4; ++j) y_lds[sg * 4 + 128 * e + j][r] = v[j];
        }
    }
    // ---- stage h(0) = h0 (immutable input) ----
    {
        const int r = tid >> 5, sg = tid & 31;
        const int swz0 = (r & 7) << 4;
        const float* hr = h0 + (size_t)(16 * s + r) * 1024 + sg * 32;
        char* db = (char*)h_lds + r * 2048;
        #pragma unroll
        for (int v = 0; v < 4; ++v) {
            f32x4 a0 = *(const f32x4*)(hr + 8 * v);
            f32x4 a1 = *(const f32x4*)(hr + 8 * v + 4);
            half8 hv;
            hv[0]=(_Float16)a0[0]; hv[1]=(_Float16)a0[1];
            hv[2]=(_Float16)a0[2]; hv[3]=(_Float16)a0[3];
            hv[4]=(_Float16)a1[0]; hv[5]=(_Float16)a1[1];
            hv[6]=(_Float16)a1[2]; hv[7]=(_Float16)a1[3];
            *(half8*)(db + ((sg * 64 + 16 * v) ^ swz0)) = hv;
        }
    }
    __syncthreads();

    const int bb  = n * 2048 + 16 * q4;   // B-frag base byte (pre-swizzle)
    const int swz = (n & 7) << 4;
    const volatile unsigned* fpoll = flags + (((s << 5) + (l & 31)) << 5);

    // 8 independent busywork chains (register-only, DCE-proof via asm pin).
    float j0 = 1.0f + 1e-7f * (float)tid, j1 = j0 + 0.1f, j2 = j0 + 0.2f, j3 = j0 + 0.3f;
    float j4 = j0 + 0.4f, j5 = j0 + 0.5f, j6 = j0 + 0.6f, j7 = j0 + 0.7f;

    for (int t = 0; t < T_STEPS; ++t) {
        if (t > 0) {
            if (wid == 0) {
                // ---- wave0: poll 32 flags, per-iteration L1 invalidate ----
                int guard = 0;
                for (;;) {
                    unsigned fv = *fpoll;
                    if (__all((int)(fv >= (unsigned)t))) break;
                    if (++guard > (1 << 15)) break;
                    __builtin_amdgcn_fence(__ATOMIC_ACQUIRE, "agent");  // waitcnt + buffer_inv
                }
                __builtin_amdgcn_fence(__ATOMIC_ACQUIRE, "agent");      // L1 clean for staging
            } else {
                // ---- waves 1-7: register-only busywork to hold DPM clocks up ----
                #pragma unroll 4
                for (int b = 0; b < BUSY_N; ++b) {
                    j0 = __builtin_fmaf(j0, 1.0000001f, 1e-9f);
                    j1 = __builtin_fmaf(j1, 1.0000002f, 1e-9f);
                    j2 = __builtin_fmaf(j2, 1.0000003f, 1e-9f);
                    j3 = __builtin_fmaf(j3, 1.0000004f, 1e-9f);
                    j4 = __builtin_fmaf(j4, 1.0000005f, 1e-9f);
                    j5 = __builtin_fmaf(j5, 1.0000006f, 1e-9f);
                    j6 = __builtin_fmaf(j6, 1.0000007f, 1e-9f);
                    j7 = __builtin_fmaf(j7, 1.0000008f, 1e-9f);
                }
                // pin: ordered wrt barriers, cannot be sunk or folded away
                asm volatile("" : "+v"(j0), "+v"(j1), "+v"(j2), "+v"(j3),
                                  "+v"(j4), "+v"(j5), "+v"(j6), "+v"(j7));
            }
            __syncthreads();
            // ---- stage h(t): 32KB plain loads (local L2 hits), jj-rotated order ----
            const unsigned long long* gb = ((t & 1) ? hbuf1 : hbuf0) + (s << 12);
            #pragma unroll
            for (int i = 0; i < 8; ++i) {
                const int F = ((i * 512 + tid) + (jj << 9)) & 4095;   // rotate start chunk
                unsigned long long v = gb[F];
                const int n2 = (F >> 3) & 15;
                const int off = ((n2 * 2048) + ((F >> 7) << 6) + ((F & 7) << 3))
                                ^ ((n2 & 7) << 4);
                *(unsigned long long*)((char*)h_lds + off) = v;
            }
            __syncthreads();
        }

        // ---- MFMA: 16 units x 16 batches, full K=1024, 4 independent chains ----
        f32x4 ac0 = {0.f,0.f,0.f,0.f}, ac1 = {0.f,0.f,0.f,0.f};
        f32x4 ac2 = {0.f,0.f,0.f,0.f}, ac3 = {0.f,0.f,0.f,0.f};
        {
            const char* hb = (const char*)h_lds;
            #pragma unroll
            for (int c = 0; c < 8; ++c) {
                half8 b0 = *(const half8*)(hb + ((bb + 64 * c) ^ swz));
                half8 b1 = *(const half8*)(hb + ((bb + 64 * (c + 8)) ^ swz));
                half8 b2 = *(const half8*)(hb + ((bb + 1024 + 64 * c) ^ swz));
                half8 b3 = *(const half8*)(hb + ((bb + 1024 + 64 * (c + 8)) ^ swz));
                ac0 = __builtin_amdgcn_mfma_f32_16x16x32_f16(wfrag[c],      b0, ac0, 0, 0, 0);
                ac1 = __builtin_amdgcn_mfma_f32_16x16x32_f16(wfrag[c + 8],  b1, ac1, 0, 0, 0);
                ac2 = __builtin_amdgcn_mfma_f32_16x16x32_f16(wfrag[c + 16], b2, ac2, 0, 0, 0);
                ac3 = __builtin_amdgcn_mfma_f32_16x16x32_f16(wfrag[c + 24], b3, ac3, 0, 0, 0);
            }
        }
        // ---- epilogue ----
        {
            const float yt = y_lds[t][n];
            float gi = (ac0[0] + ac1[0]) + (ac2[0] + ac3[0]) + yt * wih_r[0] + bias_r[0];
            float gf = (ac0[1] + ac1[1]) + (ac2[1] + ac3[1]) + yt * wih_r[1] + bias_r[1];
            float gg = (ac0[2] + ac1[2]) + (ac2[2] + ac3[2]) + yt * wih_r[2] + bias_r[2];
            float go = (ac0[3] + ac1[3]) + (ac2[3] + ac3[3]) + yt * wih_r[3] + bias_r[3];
            float cn = sigf(gf) * creg + sigf(gi) * tanhf_fast(gg);
            creg = cn;
            float hv = sigf(go) * tanhf_fast(cn);
            ((_Float16*)hout_lds)[n * 32 + u_e] = (_Float16)hv;
            if (t == T_STEPS - 1) {
                hfin[(size_t)(16 * s + n) * 1024 + 32 * jj + u_e] = hv;  // fp32 h_T
                asm volatile("s_waitcnt vmcnt(0)" ::: "memory");  // drain before flag 512
            }
        }
        __syncthreads();
        // ---- publish h(t+1): wave0 coalesced stores (write-through) -> ack -> flag ----
        if (wid == 0) {
            unsigned long long* ob = ((t & 1) ? hbuf0 : hbuf1) + (s << 12) + (jj << 7);
            ob[l]      = hout_lds[l];
            ob[l + 64] = hout_lds[l + 64];
            asm volatile("s_waitcnt vmcnt(0)" ::: "memory");   // data acked by L2
            if (l == 0)
                *(volatile unsigned*)&flags[((s << 5) + jj) << 5] = (unsigned)(t + 1);
        }
    }

    // ---- final FC: WG (s, jj<16) -> batch b = 16s+jj (hfin fp32, same XCD) ----
    if (jj < 16) {
        if (wid == 0) {
            int guard = 0;
            for (;;) {
                unsigned fv = *fpoll;
                if (__all((int)(fv >= (unsigned)T_STEPS))) break;
                if (++guard > (1 << 15)) break;
                __builtin_amdgcn_fence(__ATOMIC_ACQUIRE, "agent");
            }
            __builtin_amdgcn_fence(__ATOMIC_ACQUIRE, "agent");
        }
        __syncthreads();
        __builtin_amdgcn_fence(__ATOMIC_ACQUIRE, "agent");  // every wave: L1 clean
        float* hT  = (float*)h_lds;       // 4KB
        float* red = hT + 1024;           // 2KB
        const int b = 16 * s + jj;
        if (tid < 256) {
            f32x4 v = *(const f32x4*)(hfin + (size_t)b * 1024 + tid * 4);
            *(f32x4*)(hT + tid * 4) = v;
        }
        __syncthreads();
        {
            const int o = tid & 127, kq = tid >> 7;
            const float* wr = fc_W + (size_t)o * 1024 + kq * 256;
            const float* hp = hT + kq * 256;
            float p = 0.0f;
            #pragma unroll 8
            for (int i = 0; i < 256; i += 4) {
                f32x4 a = *(const f32x4*)(hp + i);
                f32x4 w = *(const f32x4*)(wr + i);
                p += a[0]*w[0] + a[1]*w[1] + a[2]*w[2] + a[3]*w[3];
            }
            red[kq * 128 + o] = p;
        }
        __syncthreads();
        if (tid < 128) {
            out[(size_t)b * 128 + tid] =
                red[tid] + red[128 + tid] + red[256 + tid] + red[384 + tid] + fc_b[tid];
        }
    }
}

extern "C" void kernel_launch(void* const* d_in, const int* in_sizes, int n_in,
                              void* d_out, int out_size, void* d_ws, size_t ws_size,
                              hipStream_t stream) {
    (void)in_sizes; (void)n_in; (void)out_size; (void)ws_size;
    const float* y_hist = (const float*)d_in[0];
    const float* W_ih   = (const float*)d_in[1];
    const float* W_hh   = (const float*)d_in[2];
    const float* b_ih   = (const float*)d_in[3];
    const float* b_hh   = (const float*)d_in[4];
    const float* fc_W   = (const float*)d_in[5];
    const float* fc_b   = (const float*)d_in[6];
    const float* h0     = (const float*)d_in[7];
    const float* c0     = (const float*)d_in[8];

    // d_ws: hbuf0 (256KB) | hbuf1 (256KB) | hfin (512KB) | flags (32KB, 128B-strided)
    //       | xcnt (128B) | gbar (128B)
    char* ws = (char*)d_ws;
    unsigned long long* hbuf0 = (unsigned long long*)ws;
    unsigned long long* hbuf1 = (unsigned long long*)(ws + (256 << 10));
    float*    hfin  = (float*)(ws + (512 << 10));
    unsigned int* flags = (unsigned int*)(ws + (1024 << 10));
    unsigned int* xcnt  = (unsigned int*)(ws + (1024 << 10) + (32 << 10));
    unsigned int* gbar  = (unsigned int*)(ws + (1024 << 10) + (32 << 10) + 128);

    // xcnt/gbar touched only via MALL-scope atomics -> SDMA memset safe.
    // flags reset in-kernel (stale XCD-L2 lines can't be fixed by SDMA).
    hipMemsetAsync(ws + (1024 << 10) + (32 << 10), 0, 1024, stream);
    // 16KB dynamic LDS pad -> ~81KB/WG -> 1 WG/CU -> 32 WGs per XCD.
    hipLaunchKernelGGL(lstm_persist, dim3(256), dim3(512), 16384, stream,
                       y_hist, W_ih, W_hh, b_ih, b_hh, fc_W, fc_b, h0, c0,
                       (float*)d_out, hbuf0, hbuf1, hfin, flags, xcnt, gbar);
}